// Round 1
// baseline (514.170 us; speedup 1.0000x reference)
//
#include <hip/hip_runtime.h>
#include <hip/hip_bf16.h>

#define N 8192
#define KDEG 8
#define ALPHA 64
#define DH 256

__device__ __forceinline__ float wave_reduce_sum(float v) {
#pragma unroll
    for (int off = 32; off > 0; off >>= 1) v += __shfl_xor(v, off, 64);
    return v;
}

// ---------------- Layer 0: one-hot gather + tree aggregation + ReLU ----------
// H[n][d] = relu(Ws0[t_n][d] + b0[d] + sum_{valid children c} Wn0[t_c][d])
__global__ __launch_bounds__(DH) void k_embed(const int* __restrict__ nt,
                                              const float* __restrict__ Ws0,
                                              const float* __restrict__ Wn0,
                                              const float* __restrict__ b0,
                                              float* __restrict__ H) {
    int n = blockIdx.x;
    int d = threadIdx.x;
    int t = nt[n];
    float acc = Ws0[t * DH + d] + b0[d];
    int cbase = n * KDEG + 1;
#pragma unroll
    for (int k = 0; k < KDEG; k++) {
        int c = cbase + k;
        if (c < N) acc += Wn0[nt[c] * DH + d];
    }
    H[n * DH + d] = fmaxf(acc, 0.0f);
}

// ---------------- Fused dual GEMM: S = H@Ws, M = H@Wn  (N x DH x DH) ---------
// 16 rows per block, 256 threads; thread = output column. FMA-bound inner loop.
__global__ __launch_bounds__(256) void k_gemm2(const float* __restrict__ H,
                                               const float* __restrict__ Ws,
                                               const float* __restrict__ Wn,
                                               float* __restrict__ S,
                                               float* __restrict__ M) {
    __shared__ float Hs[16 * DH];  // 16 KB
    int n0 = blockIdx.x * 16;
    int tid = threadIdx.x;
#pragma unroll
    for (int i = 0; i < 16; i++) Hs[i * DH + tid] = H[(size_t)(n0 + i) * DH + tid];
    __syncthreads();

    float accS[16], accM[16];
#pragma unroll
    for (int i = 0; i < 16; i++) { accS[i] = 0.f; accM[i] = 0.f; }

    for (int k = 0; k < DH; k += 4) {
        float ws0 = Ws[(k + 0) * DH + tid];
        float ws1 = Ws[(k + 1) * DH + tid];
        float ws2 = Ws[(k + 2) * DH + tid];
        float ws3 = Ws[(k + 3) * DH + tid];
        float wn0 = Wn[(k + 0) * DH + tid];
        float wn1 = Wn[(k + 1) * DH + tid];
        float wn2 = Wn[(k + 2) * DH + tid];
        float wn3 = Wn[(k + 3) * DH + tid];
#pragma unroll
        for (int i = 0; i < 16; i++) {
            float4 h = *reinterpret_cast<const float4*>(&Hs[i * DH + k]);
            accS[i] += h.x * ws0; accS[i] += h.y * ws1;
            accS[i] += h.z * ws2; accS[i] += h.w * ws3;
            accM[i] += h.x * wn0; accM[i] += h.y * wn1;
            accM[i] += h.z * wn2; accM[i] += h.w * wn3;
        }
    }
#pragma unroll
    for (int i = 0; i < 16; i++) {
        S[(size_t)(n0 + i) * DH + tid] = accS[i];
        M[(size_t)(n0 + i) * DH + tid] = accM[i];
    }
}

// ---------------- Combine: H = relu(S + b + sum children M) ------------------
__global__ __launch_bounds__(DH) void k_combine(const float* __restrict__ S,
                                                const float* __restrict__ M,
                                                const float* __restrict__ b,
                                                float* __restrict__ H) {
    int n = blockIdx.x;
    int d = threadIdx.x;
    float acc = S[(size_t)n * DH + d] + b[d];
    int cbase = n * KDEG + 1;
#pragma unroll
    for (int k = 0; k < KDEG; k++) {
        int c = cbase + k;
        if (c < N) acc += M[(size_t)c * DH + d];
    }
    H[(size_t)n * DH + d] = fmaxf(acc, 0.0f);
}

// ---------------- Per-node scalar dots: delta, ciu, civ, cnu, cnv ------------
// One wave per node (4 nodes / 256-thread block). aux[n*8+{0..4}].
__global__ __launch_bounds__(256) void k_scalars(const float* __restrict__ H,
                                                 const float* __restrict__ we,
                                                 const float* __restrict__ be,
                                                 const float* __restrict__ ciu_w,
                                                 const float* __restrict__ ciu_b,
                                                 const float* __restrict__ civ_w,
                                                 const float* __restrict__ civ_b,
                                                 const float* __restrict__ cnu_w,
                                                 const float* __restrict__ cnu_b,
                                                 const float* __restrict__ cnv_w,
                                                 const float* __restrict__ cnv_b,
                                                 float* __restrict__ aux,
                                                 float* __restrict__ delta_out) {
    int n = blockIdx.x * 4 + (threadIdx.x >> 6);
    int j = threadIdx.x & 63;
    const float* h = H + (size_t)n * DH;
    float h0 = h[j], h1 = h[j + 64], h2 = h[j + 128], h3 = h[j + 192];
    float pd = h0 * we[j]    + h1 * we[j + 64]    + h2 * we[j + 128]    + h3 * we[j + 192];
    float p1 = h0 * ciu_w[j] + h1 * ciu_w[j + 64] + h2 * ciu_w[j + 128] + h3 * ciu_w[j + 192];
    float p2 = h0 * civ_w[j] + h1 * civ_w[j + 64] + h2 * civ_w[j + 128] + h3 * civ_w[j + 192];
    float p3 = h0 * cnu_w[j] + h1 * cnu_w[j + 64] + h2 * cnu_w[j + 128] + h3 * cnu_w[j + 192];
    float p4 = h0 * cnv_w[j] + h1 * cnv_w[j + 64] + h2 * cnv_w[j + 128] + h3 * cnv_w[j + 192];
    pd = wave_reduce_sum(pd);
    p1 = wave_reduce_sum(p1);
    p2 = wave_reduce_sum(p2);
    p3 = wave_reduce_sum(p3);
    p4 = wave_reduce_sum(p4);
    if (j == 0) {
        float d = pd + be[0];
        aux[n * 8 + 0] = d;
        aux[n * 8 + 1] = p1 + ciu_b[0];
        aux[n * 8 + 2] = p2 + civ_b[0];
        aux[n * 8 + 3] = p3 + cnu_b[0];
        aux[n * 8 + 4] = p4 + cnv_b[0];
        delta_out[n] = d;
    }
}

// ---------------- types = H @ Wt + bt  (N x 256 x 64) ------------------------
// 16 rows / block; thread (g,j) computes rows g,g+4,g+8,g+12 at column j.
__global__ __launch_bounds__(256) void k_types(const float* __restrict__ H,
                                               const float* __restrict__ Wt,
                                               const float* __restrict__ bt,
                                               float* __restrict__ types_out) {
    __shared__ float Hs[16 * DH];
    int n0 = blockIdx.x * 16;
    int tid = threadIdx.x;
#pragma unroll
    for (int i = 0; i < 16; i++) Hs[i * DH + tid] = H[(size_t)(n0 + i) * DH + tid];
    __syncthreads();
    int j = tid & 63, g = tid >> 6;
    float acc[4];
#pragma unroll
    for (int r = 0; r < 4; r++) acc[r] = bt[j];
    for (int k = 0; k < DH; k += 4) {
        float w0 = Wt[(k + 0) * ALPHA + j];
        float w1 = Wt[(k + 1) * ALPHA + j];
        float w2 = Wt[(k + 2) * ALPHA + j];
        float w3 = Wt[(k + 3) * ALPHA + j];
#pragma unroll
        for (int r = 0; r < 4; r++) {
            float4 h4 = *reinterpret_cast<const float4*>(&Hs[(g + 4 * r) * DH + k]);
            acc[r] += h4.x * w0 + h4.y * w1 + h4.z * w2 + h4.w * w3;
        }
    }
#pragma unroll
    for (int r = 0; r < 4; r++)
        types_out[(size_t)(n0 + g + 4 * r) * ALPHA + j] = acc[r];
}

// ---------------- Child heads: dots, s_idx, s_num -> Cidx, Cnum --------------
// One wave per node; parent.child dots via shuffle reduction.
__global__ __launch_bounds__(256) void k_childheads(const float* __restrict__ H,
                                                    const float* __restrict__ aux,
                                                    const float* __restrict__ ciw_w,
                                                    const float* __restrict__ ciw_b,
                                                    const float* __restrict__ cnw_w,
                                                    const float* __restrict__ cnw_b,
                                                    float* __restrict__ cidx_out,
                                                    float* __restrict__ cnum_out) {
    int n = blockIdx.x * 4 + (threadIdx.x >> 6);
    int j = threadIdx.x & 63;
    const float* h = H + (size_t)n * DH;
    float h0 = h[j], h1 = h[j + 64], h2 = h[j + 128], h3 = h[j + 192];
    float delta = aux[n * 8 + 0];
    bool active = (delta >= 0.5f) && (n * KDEG + 1 < N);
    float ciu_n = aux[n * 8 + 1];
    float cnu_n = aux[n * 8 + 3];
    float iw = ciw_w[0], ib = ciw_b[0], nw = cnw_w[0], nb = cnw_b[0];

    float my_si = 0.f, my_sn = 0.f;  // lane k holds s_idx[k]/s_num[k] (k<8)
#pragma unroll
    for (int k = 0; k < KDEG; k++) {
        int c = n * KDEG + 1 + k;
        float si = 0.f, sn = 0.f;
        if (c < N) {  // wave-uniform branch
            const float* hc = H + (size_t)c * DH;
            float p = h0 * hc[j] + h1 * hc[j + 64] + h2 * hc[j + 128] + h3 * hc[j + 192];
            p = wave_reduce_sum(p);
            if (active) {
                si = ciu_n + aux[c * 8 + 2] + iw * p + ib;
                sn = cnu_n + aux[c * 8 + 4] + nw * p + nb;
            }
        }
        if (j == k) { my_si = si; my_sn = sn; }
    }
    if (j < KDEG) cnum_out[(size_t)n * KDEG + j] = my_sn;
    // Cidx[n][0] = -1 - s[0]; [j]=s[j-1]-s[j] for 1<=j<8; [8]=s[7]
    float prev = __shfl(my_si, (j >= 1) ? (j - 1) : 0, 64);
    float val;
    if (j == 0)            val = -1.f - my_si;
    else if (j < KDEG)     val = prev - my_si;
    else                   val = prev;  // j == 8: s[7]
    if (j <= KDEG) cidx_out[(size_t)n * (KDEG + 1) + j] = val;
}

extern "C" void kernel_launch(void* const* d_in, const int* in_sizes, int n_in,
                              void* d_out, int out_size, void* d_ws, size_t ws_size,
                              hipStream_t stream) {
    const int* nt = (const int*)d_in[0];
    // d_in[1]=children, d_in[2]=child_mask, d_in[3]=A : all structurally
    // determined by (n,k) for this problem -> never loaded.
    const float* Ws0 = (const float*)d_in[4];
    const float* Wn0 = (const float*)d_in[5];
    const float* b0  = (const float*)d_in[6];
    const float* Ws1 = (const float*)d_in[7];
    const float* Wn1 = (const float*)d_in[8];
    const float* b1  = (const float*)d_in[9];
    const float* Ws2 = (const float*)d_in[10];
    const float* Wn2 = (const float*)d_in[11];
    const float* b2  = (const float*)d_in[12];
    const float* we  = (const float*)d_in[13];
    const float* be  = (const float*)d_in[14];
    const float* Wt  = (const float*)d_in[15];
    const float* bt  = (const float*)d_in[16];
    const float* ciu_w = (const float*)d_in[17];
    const float* ciu_b = (const float*)d_in[18];
    const float* civ_w = (const float*)d_in[19];
    const float* civ_b = (const float*)d_in[20];
    const float* ciw_w = (const float*)d_in[21];
    const float* ciw_b = (const float*)d_in[22];
    const float* cnu_w = (const float*)d_in[23];
    const float* cnu_b = (const float*)d_in[24];
    const float* cnv_w = (const float*)d_in[25];
    const float* cnv_b = (const float*)d_in[26];
    const float* cnw_w = (const float*)d_in[27];
    const float* cnw_b = (const float*)d_in[28];

    float* H   = (float*)d_ws;            // N*DH
    float* S   = H + (size_t)N * DH;      // N*DH
    float* M   = S + (size_t)N * DH;      // N*DH
    float* aux = M + (size_t)N * DH;      // N*8

    float* delta_out = (float*)d_out;                       // N
    float* types_out = delta_out + N;                       // N*ALPHA
    float* cidx_out  = types_out + (size_t)N * ALPHA;       // N*(K+1)
    float* cnum_out  = cidx_out + (size_t)N * (KDEG + 1);   // N*K

    // Layer 0 (gather form)
    k_embed<<<N, DH, 0, stream>>>(nt, Ws0, Wn0, b0, H);
    // Layer 1
    k_gemm2<<<N / 16, 256, 0, stream>>>(H, Ws1, Wn1, S, M);
    k_combine<<<N, DH, 0, stream>>>(S, M, b1, H);
    // Layer 2
    k_gemm2<<<N / 16, 256, 0, stream>>>(H, Ws2, Wn2, S, M);
    k_combine<<<N, DH, 0, stream>>>(S, M, b2, H);
    // Heads
    k_scalars<<<N / 4, 256, 0, stream>>>(H, we, be, ciu_w, ciu_b, civ_w, civ_b,
                                         cnu_w, cnu_b, cnv_w, cnv_b, aux, delta_out);
    k_types<<<N / 16, 256, 0, stream>>>(H, Wt, bt, types_out);
    k_childheads<<<N / 4, 256, 0, stream>>>(H, aux, ciw_w, ciw_b, cnw_w, cnw_b,
                                            cidx_out, cnum_out);
}

// Round 2
// 422.061 us; speedup vs baseline: 1.2182x; 1.2182x over previous
//
#include <hip/hip_runtime.h>
#include <hip/hip_bf16.h>

#define N 8192
#define KDEG 8
#define ALPHA 64
#define DH 256

typedef unsigned short ushort_t;
typedef __attribute__((ext_vector_type(8))) short short8;   // 8 bf16 (4 VGPRs) MFMA frag
typedef __attribute__((ext_vector_type(4))) float f32x4;
typedef __attribute__((ext_vector_type(4))) unsigned short ushort4_t;

__device__ __forceinline__ float wave_reduce_sum(float v) {
#pragma unroll
    for (int off = 32; off > 0; off >>= 1) v += __shfl_xor(v, off, 64);
    return v;
}

__device__ __forceinline__ ushort_t bf16_of(float x) {
    __hip_bfloat16 h = __float2bfloat16(x);
    return *(ushort_t*)&h;
}
__device__ __forceinline__ float f_of_bf16(ushort_t u) {
    __hip_bfloat16 h = *(__hip_bfloat16*)&u;
    return __bfloat162float(h);
}

// ---- pack weights into MFMA B-fragment order, split hi/lo bf16 --------------
// packed[((t*8 + kb)*64 + lane)*8 + j] = W[kb*32 + (lane>>4)*8 + j][t*16 + (lane&15)]
// Matrices 0..3: 256x256 (Ws1,Wn1,Ws2,Wn2) at offsets m*65536; matrix 4: Wt 256x64 at 262144.
__global__ __launch_bounds__(256) void k_pack(const float* __restrict__ W0,
                                              const float* __restrict__ W1,
                                              const float* __restrict__ W2,
                                              const float* __restrict__ W3,
                                              const float* __restrict__ W4,
                                              ushort_t* __restrict__ Phi,
                                              ushort_t* __restrict__ Plo) {
    int e = blockIdx.x * 256 + threadIdx.x;
    if (e >= 262144 + 16384) return;
    const float* W;
    int o, Ncols;
    if (e < 262144) {
        int m = e >> 16; o = e & 65535; Ncols = 256;
        W = (m == 0) ? W0 : (m == 1) ? W1 : (m == 2) ? W2 : W3;
    } else {
        o = e - 262144; Ncols = 64; W = W4;
    }
    int j = o & 7, l = (o >> 3) & 63, r = o >> 9;
    int kb = r & 7, t = r >> 3;
    int k = kb * 32 + (l >> 4) * 8 + j;
    int c = t * 16 + (l & 15);
    float v = W[k * Ncols + c];
    ushort_t h = bf16_of(v);
    Phi[e] = h;
    Plo[e] = bf16_of(v - f_of_bf16(h));
}

// ---- layer 0: one-hot gather + tree agg + relu -> Hhi/Hlo -------------------
__global__ __launch_bounds__(256) void k_embed(const int* __restrict__ nt,
                                               const float* __restrict__ Ws0,
                                               const float* __restrict__ Wn0,
                                               const float* __restrict__ b0,
                                               ushort_t* __restrict__ Hhi,
                                               ushort_t* __restrict__ Hlo) {
    int g = blockIdx.x * 256 + threadIdx.x;  // [0, N*64)
    int n = g >> 6, d = (g & 63) * 4;
    int t = nt[n];
    f32x4 acc = *(const f32x4*)(b0 + d);
    acc += *(const f32x4*)(Ws0 + t * DH + d);
    int cb = n * KDEG + 1;
#pragma unroll
    for (int k = 0; k < KDEG; k++) {
        int c = cb + k;
        if (c < N) acc += *(const f32x4*)(Wn0 + nt[c] * DH + d);
    }
    ushort4_t hi, lo;
#pragma unroll
    for (int i = 0; i < 4; i++) {
        float x = fmaxf(acc[i], 0.0f);
        ushort_t h = bf16_of(x);
        hi[i] = h;
        lo[i] = bf16_of(x - f_of_bf16(h));
    }
    *(ushort4_t*)(Hhi + (size_t)n * DH + d) = hi;
    *(ushort4_t*)(Hlo + (size_t)n * DH + d) = lo;
}

// ---- MFMA dual GEMM: S = H@Ws, M = H@Wn, split-bf16 (3 MFMAs / tile-step) ---
// wave = 32 rows x 64 cols of one output. 2048 waves = 512 blocks.
__global__ __launch_bounds__(256) void k_gemm(const ushort_t* __restrict__ Hhi,
                                              const ushort_t* __restrict__ Hlo,
                                              const ushort_t* __restrict__ PShi,
                                              const ushort_t* __restrict__ PSlo,
                                              const ushort_t* __restrict__ PNhi,
                                              const ushort_t* __restrict__ PNlo,
                                              float* __restrict__ S,
                                              float* __restrict__ M) {
    int w = blockIdx.x * 4 + (threadIdx.x >> 6);
    int lane = threadIdx.x & 63;
    int rg = w >> 3, mat = (w >> 2) & 1, cg = w & 3;
    const ushort_t* Bh = mat ? PNhi : PShi;
    const ushort_t* Bl = mat ? PNlo : PSlo;
    float* Out = mat ? M : S;
    int r0 = rg * 32, c0 = cg * 64;
    int mrow = lane & 15, quad = lane >> 4;

    f32x4 acc[2][4] = {};
    const ushort_t* ah0p = Hhi + (size_t)(r0 + mrow) * DH + quad * 8;
    const ushort_t* al0p = Hlo + (size_t)(r0 + mrow) * DH + quad * 8;
#pragma unroll
    for (int kb = 0; kb < 8; kb++) {
        short8 ah0 = *(const short8*)(ah0p + kb * 32);
        short8 ah1 = *(const short8*)(ah0p + 16 * DH + kb * 32);
        short8 al0 = *(const short8*)(al0p + kb * 32);
        short8 al1 = *(const short8*)(al0p + 16 * DH + kb * 32);
#pragma unroll
        for (int ct = 0; ct < 4; ct++) {
            int t = cg * 4 + ct;
            const ushort_t* bp = Bh + (size_t)((t * 8 + kb) * 64 + lane) * 8;
            const ushort_t* lp = Bl + (size_t)((t * 8 + kb) * 64 + lane) * 8;
            short8 bh = *(const short8*)bp;
            short8 bl = *(const short8*)lp;
            acc[0][ct] = __builtin_amdgcn_mfma_f32_16x16x32_bf16(ah0, bh, acc[0][ct], 0, 0, 0);
            acc[1][ct] = __builtin_amdgcn_mfma_f32_16x16x32_bf16(ah1, bh, acc[1][ct], 0, 0, 0);
            acc[0][ct] = __builtin_amdgcn_mfma_f32_16x16x32_bf16(ah0, bl, acc[0][ct], 0, 0, 0);
            acc[1][ct] = __builtin_amdgcn_mfma_f32_16x16x32_bf16(ah1, bl, acc[1][ct], 0, 0, 0);
            acc[0][ct] = __builtin_amdgcn_mfma_f32_16x16x32_bf16(al0, bh, acc[0][ct], 0, 0, 0);
            acc[1][ct] = __builtin_amdgcn_mfma_f32_16x16x32_bf16(al1, bh, acc[1][ct], 0, 0, 0);
        }
    }
#pragma unroll
    for (int rt = 0; rt < 2; rt++)
#pragma unroll
        for (int ct = 0; ct < 4; ct++) {
            int col = c0 + ct * 16 + mrow;
            int rowb = r0 + rt * 16 + quad * 4;
#pragma unroll
            for (int r = 0; r < 4; r++)
                Out[(size_t)(rowb + r) * DH + col] = acc[rt][ct][r];
        }
}

// ---- combine: H = relu(S + b + sum children M); emit f32 + hi/lo ------------
__global__ __launch_bounds__(256) void k_combine(const float* __restrict__ S,
                                                 const float* __restrict__ M,
                                                 const float* __restrict__ b,
                                                 float* __restrict__ Hf,
                                                 ushort_t* __restrict__ Hhi,
                                                 ushort_t* __restrict__ Hlo) {
    int g = blockIdx.x * 256 + threadIdx.x;
    int n = g >> 6, d = (g & 63) * 4;
    f32x4 acc = *(const f32x4*)(S + (size_t)n * DH + d);
    acc += *(const f32x4*)(b + d);
    int cb = n * KDEG + 1;
#pragma unroll
    for (int k = 0; k < KDEG; k++) {
        int c = cb + k;
        if (c < N) acc += *(const f32x4*)(M + (size_t)c * DH + d);
    }
    f32x4 relu;
    ushort4_t hi, lo;
#pragma unroll
    for (int i = 0; i < 4; i++) {
        float x = fmaxf(acc[i], 0.0f);
        relu[i] = x;
        ushort_t h = bf16_of(x);
        hi[i] = h;
        lo[i] = bf16_of(x - f_of_bf16(h));
    }
    *(f32x4*)(Hf + (size_t)n * DH + d) = relu;
    *(ushort4_t*)(Hhi + (size_t)n * DH + d) = hi;
    *(ushort4_t*)(Hlo + (size_t)n * DH + d) = lo;
}

// ---- per-node scalar dots: delta, ciu, civ, cnu, cnv ------------------------
__global__ __launch_bounds__(256) void k_scalars(const float* __restrict__ H,
                                                 const float* __restrict__ we,
                                                 const float* __restrict__ be,
                                                 const float* __restrict__ ciu_w,
                                                 const float* __restrict__ ciu_b,
                                                 const float* __restrict__ civ_w,
                                                 const float* __restrict__ civ_b,
                                                 const float* __restrict__ cnu_w,
                                                 const float* __restrict__ cnu_b,
                                                 const float* __restrict__ cnv_w,
                                                 const float* __restrict__ cnv_b,
                                                 float* __restrict__ aux,
                                                 float* __restrict__ delta_out) {
    int n = blockIdx.x * 4 + (threadIdx.x >> 6);
    int j = threadIdx.x & 63;
    const float* h = H + (size_t)n * DH;
    float h0 = h[j], h1 = h[j + 64], h2 = h[j + 128], h3 = h[j + 192];
    float pd = h0 * we[j]    + h1 * we[j + 64]    + h2 * we[j + 128]    + h3 * we[j + 192];
    float p1 = h0 * ciu_w[j] + h1 * ciu_w[j + 64] + h2 * ciu_w[j + 128] + h3 * ciu_w[j + 192];
    float p2 = h0 * civ_w[j] + h1 * civ_w[j + 64] + h2 * civ_w[j + 128] + h3 * civ_w[j + 192];
    float p3 = h0 * cnu_w[j] + h1 * cnu_w[j + 64] + h2 * cnu_w[j + 128] + h3 * cnu_w[j + 192];
    float p4 = h0 * cnv_w[j] + h1 * cnv_w[j + 64] + h2 * cnv_w[j + 128] + h3 * cnv_w[j + 192];
    pd = wave_reduce_sum(pd);
    p1 = wave_reduce_sum(p1);
    p2 = wave_reduce_sum(p2);
    p3 = wave_reduce_sum(p3);
    p4 = wave_reduce_sum(p4);
    if (j == 0) {
        float d = pd + be[0];
        aux[n * 8 + 0] = d;
        aux[n * 8 + 1] = p1 + ciu_b[0];
        aux[n * 8 + 2] = p2 + civ_b[0];
        aux[n * 8 + 3] = p3 + cnu_b[0];
        aux[n * 8 + 4] = p4 + cnv_b[0];
        delta_out[n] = d;
    }
}

// ---- types = H @ Wt + bt via MFMA (split-bf16) ------------------------------
// wave = 16 rows x 64 cols. 512 waves = 128 blocks.
__global__ __launch_bounds__(256) void k_types(const ushort_t* __restrict__ Hhi,
                                               const ushort_t* __restrict__ Hlo,
                                               const ushort_t* __restrict__ Bh,
                                               const ushort_t* __restrict__ Bl,
                                               const float* __restrict__ bt,
                                               float* __restrict__ out) {
    int w = blockIdx.x * 4 + (threadIdx.x >> 6);  // row-tile
    int lane = threadIdx.x & 63;
    int mrow = lane & 15, quad = lane >> 4;
    int r0 = w * 16;
    f32x4 acc[4] = {};
    const ushort_t* ap = Hhi + (size_t)(r0 + mrow) * DH + quad * 8;
    const ushort_t* lp = Hlo + (size_t)(r0 + mrow) * DH + quad * 8;
#pragma unroll
    for (int kb = 0; kb < 8; kb++) {
        short8 ah = *(const short8*)(ap + kb * 32);
        short8 al = *(const short8*)(lp + kb * 32);
#pragma unroll
        for (int ct = 0; ct < 4; ct++) {
            short8 bh = *(const short8*)(Bh + (size_t)((ct * 8 + kb) * 64 + lane) * 8);
            short8 bl = *(const short8*)(Bl + (size_t)((ct * 8 + kb) * 64 + lane) * 8);
            acc[ct] = __builtin_amdgcn_mfma_f32_16x16x32_bf16(ah, bh, acc[ct], 0, 0, 0);
            acc[ct] = __builtin_amdgcn_mfma_f32_16x16x32_bf16(ah, bl, acc[ct], 0, 0, 0);
            acc[ct] = __builtin_amdgcn_mfma_f32_16x16x32_bf16(al, bh, acc[ct], 0, 0, 0);
        }
    }
#pragma unroll
    for (int ct = 0; ct < 4; ct++) {
        float bias = bt[ct * 16 + mrow];
        int rowb = r0 + quad * 4;
#pragma unroll
        for (int r = 0; r < 4; r++)
            out[(size_t)(rowb + r) * ALPHA + ct * 16 + mrow] = acc[ct][r] + bias;
    }
}

// ---- child heads: dots, s_idx, s_num -> Cidx, Cnum --------------------------
__global__ __launch_bounds__(256) void k_childheads(const float* __restrict__ H,
                                                    const float* __restrict__ aux,
                                                    const float* __restrict__ ciw_w,
                                                    const float* __restrict__ ciw_b,
                                                    const float* __restrict__ cnw_w,
                                                    const float* __restrict__ cnw_b,
                                                    float* __restrict__ cidx_out,
                                                    float* __restrict__ cnum_out) {
    int n = blockIdx.x * 4 + (threadIdx.x >> 6);
    int j = threadIdx.x & 63;
    const float* h = H + (size_t)n * DH;
    float h0 = h[j], h1 = h[j + 64], h2 = h[j + 128], h3 = h[j + 192];
    float delta = aux[n * 8 + 0];
    bool active = (delta >= 0.5f) && (n * KDEG + 1 < N);
    float ciu_n = aux[n * 8 + 1];
    float cnu_n = aux[n * 8 + 3];
    float iw = ciw_w[0], ib = ciw_b[0], nw = cnw_w[0], nb = cnw_b[0];

    float my_si = 0.f, my_sn = 0.f;
#pragma unroll
    for (int k = 0; k < KDEG; k++) {
        int c = n * KDEG + 1 + k;
        float si = 0.f, sn = 0.f;
        if (c < N) {
            const float* hc = H + (size_t)c * DH;
            float p = h0 * hc[j] + h1 * hc[j + 64] + h2 * hc[j + 128] + h3 * hc[j + 192];
            p = wave_reduce_sum(p);
            if (active) {
                si = ciu_n + aux[c * 8 + 2] + iw * p + ib;
                sn = cnu_n + aux[c * 8 + 4] + nw * p + nb;
            }
        }
        if (j == k) { my_si = si; my_sn = sn; }
    }
    if (j < KDEG) cnum_out[(size_t)n * KDEG + j] = my_sn;
    float prev = __shfl(my_si, (j >= 1) ? (j - 1) : 0, 64);
    float val;
    if (j == 0)        val = -1.f - my_si;
    else if (j < KDEG) val = prev - my_si;
    else               val = prev;  // j == 8
    if (j <= KDEG) cidx_out[(size_t)n * (KDEG + 1) + j] = val;
}

extern "C" void kernel_launch(void* const* d_in, const int* in_sizes, int n_in,
                              void* d_out, int out_size, void* d_ws, size_t ws_size,
                              hipStream_t stream) {
    const int* nt = (const int*)d_in[0];
    // d_in[1]=children, d_in[2]=child_mask, d_in[3]=A: structurally determined, never loaded.
    const float* Ws0 = (const float*)d_in[4];
    const float* Wn0 = (const float*)d_in[5];
    const float* b0  = (const float*)d_in[6];
    const float* Ws1 = (const float*)d_in[7];
    const float* Wn1 = (const float*)d_in[8];
    const float* b1  = (const float*)d_in[9];
    const float* Ws2 = (const float*)d_in[10];
    const float* Wn2 = (const float*)d_in[11];
    const float* b2  = (const float*)d_in[12];
    const float* we  = (const float*)d_in[13];
    const float* be  = (const float*)d_in[14];
    const float* Wt  = (const float*)d_in[15];
    const float* bt  = (const float*)d_in[16];
    const float* ciu_w = (const float*)d_in[17];
    const float* ciu_b = (const float*)d_in[18];
    const float* civ_w = (const float*)d_in[19];
    const float* civ_b = (const float*)d_in[20];
    const float* ciw_w = (const float*)d_in[21];
    const float* ciw_b = (const float*)d_in[22];
    const float* cnu_w = (const float*)d_in[23];
    const float* cnu_b = (const float*)d_in[24];
    const float* cnv_w = (const float*)d_in[25];
    const float* cnv_b = (const float*)d_in[26];
    const float* cnw_w = (const float*)d_in[27];
    const float* cnw_b = (const float*)d_in[28];

    char* w = (char*)d_ws;
    float*   Hf  = (float*)(w);                         // 8 MB
    float*   S   = (float*)(w + ((size_t)8  << 20));    // 8 MB
    float*   M   = (float*)(w + ((size_t)16 << 20));    // 8 MB
    float*   aux = (float*)(w + ((size_t)24 << 20));    // 256 KB
    ushort_t* Hhi = (ushort_t*)(w + ((size_t)25 << 20)); // 4 MB
    ushort_t* Hlo = (ushort_t*)(w + ((size_t)29 << 20)); // 4 MB
    ushort_t* Phi = (ushort_t*)(w + ((size_t)33 << 20)); // ~557 KB
    ushort_t* Plo = (ushort_t*)(w + ((size_t)34 << 20)); // ~557 KB

    float* delta_out = (float*)d_out;                      // N
    float* types_out = delta_out + N;                      // N*ALPHA
    float* cidx_out  = types_out + (size_t)N * ALPHA;      // N*(K+1)
    float* cnum_out  = cidx_out + (size_t)N * (KDEG + 1);  // N*K

    // weight packing (per launch, ~1.1 MB)
    k_pack<<<1088, 256, 0, stream>>>(Ws1, Wn1, Ws2, Wn2, Wt, Phi, Plo);
    // layer 0
    k_embed<<<2048, 256, 0, stream>>>(nt, Ws0, Wn0, b0, Hhi, Hlo);
    // layer 1
    k_gemm<<<512, 256, 0, stream>>>(Hhi, Hlo, Phi + 0, Plo + 0, Phi + 65536, Plo + 65536, S, M);
    k_combine<<<2048, 256, 0, stream>>>(S, M, b1, Hf, Hhi, Hlo);
    // layer 2
    k_gemm<<<512, 256, 0, stream>>>(Hhi, Hlo, Phi + 131072, Plo + 131072, Phi + 196608, Plo + 196608, S, M);
    k_combine<<<2048, 256, 0, stream>>>(S, M, b2, Hf, Hhi, Hlo);
    // heads
    k_scalars<<<N / 4, 256, 0, stream>>>(Hf, we, be, ciu_w, ciu_b, civ_w, civ_b,
                                         cnu_w, cnu_b, cnv_w, cnv_b, aux, delta_out);
    k_types<<<128, 256, 0, stream>>>(Hhi, Hlo, Phi + 262144, Plo + 262144, bt, types_out);
    k_childheads<<<N / 4, 256, 0, stream>>>(Hf, aux, ciw_w, ciw_b, cnw_w, cnw_b,
                                            cidx_out, cnum_out);
}

// Round 3
// 410.622 us; speedup vs baseline: 1.2522x; 1.0279x over previous
//
#include <hip/hip_runtime.h>
#include <hip/hip_bf16.h>

#define N 8192
#define KDEG 8
#define ALPHA 64
#define DH 256

typedef unsigned short ushort_t;
typedef __attribute__((ext_vector_type(8))) short short8;   // 8 bf16 (4 VGPRs) MFMA frag
typedef __attribute__((ext_vector_type(4))) float f32x4;
typedef __attribute__((ext_vector_type(4))) unsigned short ushort4_t;

__device__ __forceinline__ float wave_reduce_sum(float v) {
#pragma unroll
    for (int off = 32; off > 0; off >>= 1) v += __shfl_xor(v, off, 64);
    return v;
}

__device__ __forceinline__ ushort_t bf16_of(float x) {
    __hip_bfloat16 h = __float2bfloat16(x);
    return *(ushort_t*)&h;
}
__device__ __forceinline__ float f_of_bf16(ushort_t u) {
    __hip_bfloat16 h = *(__hip_bfloat16*)&u;
    return __bfloat162float(h);
}

// ---- L1: fused [embed | weight-pack] by block range -------------------------
// blocks [0,2048): layer-0 one-hot gather + tree agg + relu -> Hhi/Hlo
// blocks [2048,3136): pack Ws1,Wn1,Ws2,Wn2,Wt into MFMA B-frag order, hi/lo.
// pack layout: P[((t*8+kb)*64+lane)*8+j] = W[kb*32+(lane>>4)*8+j][t*16+(lane&15)]
__global__ __launch_bounds__(256) void k_embed_pack(const int* __restrict__ nt,
                                                    const float* __restrict__ Ws0,
                                                    const float* __restrict__ Wn0,
                                                    const float* __restrict__ b0,
                                                    const float* __restrict__ W0,
                                                    const float* __restrict__ W1,
                                                    const float* __restrict__ W2,
                                                    const float* __restrict__ W3,
                                                    const float* __restrict__ W4,
                                                    ushort_t* __restrict__ Hhi,
                                                    ushort_t* __restrict__ Hlo,
                                                    ushort_t* __restrict__ Phi,
                                                    ushort_t* __restrict__ Plo) {
    if (blockIdx.x < 2048) {
        int g = blockIdx.x * 256 + threadIdx.x;  // [0, N*64)
        int n = g >> 6, d = (g & 63) * 4;
        int t = nt[n];
        f32x4 acc = *(const f32x4*)(b0 + d);
        acc += *(const f32x4*)(Ws0 + t * DH + d);
        int cb = n * KDEG + 1;
#pragma unroll
        for (int k = 0; k < KDEG; k++) {
            int c = cb + k;
            if (c < N) acc += *(const f32x4*)(Wn0 + nt[c] * DH + d);
        }
        ushort4_t hi, lo;
#pragma unroll
        for (int i = 0; i < 4; i++) {
            float x = fmaxf(acc[i], 0.0f);
            ushort_t h = bf16_of(x);
            hi[i] = h;
            lo[i] = bf16_of(x - f_of_bf16(h));
        }
        *(ushort4_t*)(Hhi + (size_t)n * DH + d) = hi;
        *(ushort4_t*)(Hlo + (size_t)n * DH + d) = lo;
    } else {
        int e = (blockIdx.x - 2048) * 256 + threadIdx.x;
        if (e >= 262144 + 16384) return;
        const float* W;
        int o, Ncols;
        if (e < 262144) {
            int m = e >> 16; o = e & 65535; Ncols = 256;
            W = (m == 0) ? W0 : (m == 1) ? W1 : (m == 2) ? W2 : W3;
        } else {
            o = e - 262144; Ncols = 64; W = W4;
        }
        int j = o & 7, l = (o >> 3) & 63, r = o >> 9;
        int kb = r & 7, t = r >> 3;
        int k = kb * 32 + (l >> 4) * 8 + j;
        int c = t * 16 + (l & 15);
        float v = W[k * Ncols + c];
        ushort_t h = bf16_of(v);
        Phi[e] = h;
        Plo[e] = bf16_of(v - f_of_bf16(h));
    }
}

// ---- MFMA dual GEMM: S = H@Ws, M = H@Wn, split-bf16 (3 MFMAs / tile-step) ---
// wave = 32 rows x 64 cols of one output. 2048 waves = 512 blocks.
__global__ __launch_bounds__(256) void k_gemm(const ushort_t* __restrict__ Hhi,
                                              const ushort_t* __restrict__ Hlo,
                                              const ushort_t* __restrict__ PShi,
                                              const ushort_t* __restrict__ PSlo,
                                              const ushort_t* __restrict__ PNhi,
                                              const ushort_t* __restrict__ PNlo,
                                              float* __restrict__ S,
                                              float* __restrict__ M) {
    int w = blockIdx.x * 4 + (threadIdx.x >> 6);
    int lane = threadIdx.x & 63;
    int rg = w >> 3, mat = (w >> 2) & 1, cg = w & 3;
    const ushort_t* Bh = mat ? PNhi : PShi;
    const ushort_t* Bl = mat ? PNlo : PSlo;
    float* Out = mat ? M : S;
    int r0 = rg * 32, c0 = cg * 64;
    int mrow = lane & 15, quad = lane >> 4;

    f32x4 acc[2][4] = {};
    const ushort_t* ah0p = Hhi + (size_t)(r0 + mrow) * DH + quad * 8;
    const ushort_t* al0p = Hlo + (size_t)(r0 + mrow) * DH + quad * 8;
#pragma unroll
    for (int kb = 0; kb < 8; kb++) {
        short8 ah0 = *(const short8*)(ah0p + kb * 32);
        short8 ah1 = *(const short8*)(ah0p + 16 * DH + kb * 32);
        short8 al0 = *(const short8*)(al0p + kb * 32);
        short8 al1 = *(const short8*)(al0p + 16 * DH + kb * 32);
#pragma unroll
        for (int ct = 0; ct < 4; ct++) {
            int t = cg * 4 + ct;
            const ushort_t* bp = Bh + (size_t)((t * 8 + kb) * 64 + lane) * 8;
            const ushort_t* lp = Bl + (size_t)((t * 8 + kb) * 64 + lane) * 8;
            short8 bh = *(const short8*)bp;
            short8 bl = *(const short8*)lp;
            acc[0][ct] = __builtin_amdgcn_mfma_f32_16x16x32_bf16(ah0, bh, acc[0][ct], 0, 0, 0);
            acc[1][ct] = __builtin_amdgcn_mfma_f32_16x16x32_bf16(ah1, bh, acc[1][ct], 0, 0, 0);
            acc[0][ct] = __builtin_amdgcn_mfma_f32_16x16x32_bf16(ah0, bl, acc[0][ct], 0, 0, 0);
            acc[1][ct] = __builtin_amdgcn_mfma_f32_16x16x32_bf16(ah1, bl, acc[1][ct], 0, 0, 0);
            acc[0][ct] = __builtin_amdgcn_mfma_f32_16x16x32_bf16(al0, bh, acc[0][ct], 0, 0, 0);
            acc[1][ct] = __builtin_amdgcn_mfma_f32_16x16x32_bf16(al1, bh, acc[1][ct], 0, 0, 0);
        }
    }
#pragma unroll
    for (int rt = 0; rt < 2; rt++)
#pragma unroll
        for (int ct = 0; ct < 4; ct++) {
            int col = c0 + ct * 16 + mrow;
            int rowb = r0 + rt * 16 + quad * 4;
#pragma unroll
            for (int r = 0; r < 4; r++)
                Out[(size_t)(rowb + r) * DH + col] = acc[rt][ct][r];
        }
}

// ---- combine: H = relu(S + b + sum children M) -> hi/lo; optional scalar heads
// one wave per node (4 nodes / block); thread j holds cols 4j..4j+3 in regs.
template <bool WITH_SCALARS>
__global__ __launch_bounds__(256) void k_combine(const float* __restrict__ S,
                                                 const float* __restrict__ M,
                                                 const float* __restrict__ b,
                                                 ushort_t* __restrict__ Hhi,
                                                 ushort_t* __restrict__ Hlo,
                                                 const float* __restrict__ we,
                                                 const float* __restrict__ be,
                                                 const float* __restrict__ ciu_w,
                                                 const float* __restrict__ ciu_b,
                                                 const float* __restrict__ civ_w,
                                                 const float* __restrict__ civ_b,
                                                 const float* __restrict__ cnu_w,
                                                 const float* __restrict__ cnu_b,
                                                 const float* __restrict__ cnv_w,
                                                 const float* __restrict__ cnv_b,
                                                 float* __restrict__ aux,
                                                 float* __restrict__ delta_out) {
    int g = blockIdx.x * 256 + threadIdx.x;
    int n = g >> 6, j = g & 63, d = j * 4;
    f32x4 acc = *(const f32x4*)(S + (size_t)n * DH + d);
    acc += *(const f32x4*)(b + d);
    int cb = n * KDEG + 1;
#pragma unroll
    for (int k = 0; k < KDEG; k++) {
        int c = cb + k;
        if (c < N) acc += *(const f32x4*)(M + (size_t)c * DH + d);
    }
    f32x4 x;
    ushort4_t hi, lo;
#pragma unroll
    for (int i = 0; i < 4; i++) {
        x[i] = fmaxf(acc[i], 0.0f);
        ushort_t h = bf16_of(x[i]);
        hi[i] = h;
        lo[i] = bf16_of(x[i] - f_of_bf16(h));
    }
    *(ushort4_t*)(Hhi + (size_t)n * DH + d) = hi;
    *(ushort4_t*)(Hlo + (size_t)n * DH + d) = lo;

    if (WITH_SCALARS) {
        f32x4 w0 = *(const f32x4*)(we + d);
        f32x4 w1 = *(const f32x4*)(ciu_w + d);
        f32x4 w2 = *(const f32x4*)(civ_w + d);
        f32x4 w3 = *(const f32x4*)(cnu_w + d);
        f32x4 w4 = *(const f32x4*)(cnv_w + d);
        float pd = 0.f, p1 = 0.f, p2 = 0.f, p3 = 0.f, p4 = 0.f;
#pragma unroll
        for (int i = 0; i < 4; i++) {
            pd += x[i] * w0[i];
            p1 += x[i] * w1[i];
            p2 += x[i] * w2[i];
            p3 += x[i] * w3[i];
            p4 += x[i] * w4[i];
        }
        pd = wave_reduce_sum(pd);
        p1 = wave_reduce_sum(p1);
        p2 = wave_reduce_sum(p2);
        p3 = wave_reduce_sum(p3);
        p4 = wave_reduce_sum(p4);
        if (j == 0) {
            float dv = pd + be[0];
            aux[n * 8 + 0] = dv;
            aux[n * 8 + 1] = p1 + ciu_b[0];
            aux[n * 8 + 2] = p2 + civ_b[0];
            aux[n * 8 + 3] = p3 + cnu_b[0];
            aux[n * 8 + 4] = p4 + cnv_b[0];
            delta_out[n] = dv;
        }
    }
}

// ---- L6: fused [types-GEMM | child heads] by block range --------------------
// blocks [0,128): types = H @ Wt + bt via MFMA (wave = 16 rows x 64 cols)
// blocks [128, 128+2048): child dots + Cidx/Cnum (wave per node)
__global__ __launch_bounds__(256) void k_heads(const ushort_t* __restrict__ Hhi,
                                               const ushort_t* __restrict__ Hlo,
                                               const ushort_t* __restrict__ Bh,
                                               const ushort_t* __restrict__ Bl,
                                               const float* __restrict__ bt,
                                               const float* __restrict__ aux,
                                               const float* __restrict__ ciw_w,
                                               const float* __restrict__ ciw_b,
                                               const float* __restrict__ cnw_w,
                                               const float* __restrict__ cnw_b,
                                               float* __restrict__ types_out,
                                               float* __restrict__ cidx_out,
                                               float* __restrict__ cnum_out) {
    int lane = threadIdx.x & 63;
    if (blockIdx.x < 128) {
        int w = blockIdx.x * 4 + (threadIdx.x >> 6);  // row-tile
        int mrow = lane & 15, quad = lane >> 4;
        int r0 = w * 16;
        f32x4 acc[4] = {};
        const ushort_t* ap = Hhi + (size_t)(r0 + mrow) * DH + quad * 8;
        const ushort_t* lp = Hlo + (size_t)(r0 + mrow) * DH + quad * 8;
#pragma unroll
        for (int kb = 0; kb < 8; kb++) {
            short8 ah = *(const short8*)(ap + kb * 32);
            short8 al = *(const short8*)(lp + kb * 32);
#pragma unroll
            for (int ct = 0; ct < 4; ct++) {
                short8 bh = *(const short8*)(Bh + (size_t)((ct * 8 + kb) * 64 + lane) * 8);
                short8 bl = *(const short8*)(Bl + (size_t)((ct * 8 + kb) * 64 + lane) * 8);
                acc[ct] = __builtin_amdgcn_mfma_f32_16x16x32_bf16(ah, bh, acc[ct], 0, 0, 0);
                acc[ct] = __builtin_amdgcn_mfma_f32_16x16x32_bf16(ah, bl, acc[ct], 0, 0, 0);
                acc[ct] = __builtin_amdgcn_mfma_f32_16x16x32_bf16(al, bh, acc[ct], 0, 0, 0);
            }
        }
#pragma unroll
        for (int ct = 0; ct < 4; ct++) {
            float bias = bt[ct * 16 + mrow];
            int rowb = r0 + quad * 4;
#pragma unroll
            for (int r = 0; r < 4; r++)
                types_out[(size_t)(rowb + r) * ALPHA + ct * 16 + mrow] = acc[ct][r] + bias;
        }
    } else {
        int n = (blockIdx.x - 128) * 4 + (threadIdx.x >> 6);
        int j = lane, d = j * 4;
        // reconstruct parent row (f32 = hi + lo)
        ushort4_t phi = *(const ushort4_t*)(Hhi + (size_t)n * DH + d);
        ushort4_t plo = *(const ushort4_t*)(Hlo + (size_t)n * DH + d);
        float hp[4];
#pragma unroll
        for (int i = 0; i < 4; i++) hp[i] = f_of_bf16(phi[i]) + f_of_bf16(plo[i]);

        float delta = aux[n * 8 + 0];
        bool active = (delta >= 0.5f) && (n * KDEG + 1 < N);
        float ciu_n = aux[n * 8 + 1];
        float cnu_n = aux[n * 8 + 3];
        float iw = ciw_w[0], ib = ciw_b[0], nw = cnw_w[0], nb = cnw_b[0];

        float my_si = 0.f, my_sn = 0.f;
#pragma unroll
        for (int k = 0; k < KDEG; k++) {
            int c = n * KDEG + 1 + k;
            float si = 0.f, sn = 0.f;
            if (c < N) {  // wave-uniform
                ushort4_t chi = *(const ushort4_t*)(Hhi + (size_t)c * DH + d);
                ushort4_t clo = *(const ushort4_t*)(Hlo + (size_t)c * DH + d);
                float p = 0.f;
#pragma unroll
                for (int i = 0; i < 4; i++)
                    p += hp[i] * (f_of_bf16(chi[i]) + f_of_bf16(clo[i]));
                p = wave_reduce_sum(p);
                if (active) {
                    si = ciu_n + aux[c * 8 + 2] + iw * p + ib;
                    sn = cnu_n + aux[c * 8 + 4] + nw * p + nb;
                }
            }
            if (j == k) { my_si = si; my_sn = sn; }
        }
        if (j < KDEG) cnum_out[(size_t)n * KDEG + j] = my_sn;
        float prev = __shfl(my_si, (j >= 1) ? (j - 1) : 0, 64);
        float val;
        if (j == 0)        val = -1.f - my_si;
        else if (j < KDEG) val = prev - my_si;
        else               val = prev;  // j == 8
        if (j <= KDEG) cidx_out[(size_t)n * (KDEG + 1) + j] = val;
    }
}

extern "C" void kernel_launch(void* const* d_in, const int* in_sizes, int n_in,
                              void* d_out, int out_size, void* d_ws, size_t ws_size,
                              hipStream_t stream) {
    const int* nt = (const int*)d_in[0];
    // d_in[1]=children, d_in[2]=child_mask, d_in[3]=A: structurally determined, never loaded.
    const float* Ws0 = (const float*)d_in[4];
    const float* Wn0 = (const float*)d_in[5];
    const float* b0  = (const float*)d_in[6];
    const float* Ws1 = (const float*)d_in[7];
    const float* Wn1 = (const float*)d_in[8];
    const float* b1  = (const float*)d_in[9];
    const float* Ws2 = (const float*)d_in[10];
    const float* Wn2 = (const float*)d_in[11];
    const float* b2  = (const float*)d_in[12];
    const float* we  = (const float*)d_in[13];
    const float* be  = (const float*)d_in[14];
    const float* Wt  = (const float*)d_in[15];
    const float* bt  = (const float*)d_in[16];
    const float* ciu_w = (const float*)d_in[17];
    const float* ciu_b = (const float*)d_in[18];
    const float* civ_w = (const float*)d_in[19];
    const float* civ_b = (const float*)d_in[20];
    const float* ciw_w = (const float*)d_in[21];
    const float* ciw_b = (const float*)d_in[22];
    const float* cnu_w = (const float*)d_in[23];
    const float* cnu_b = (const float*)d_in[24];
    const float* cnv_w = (const float*)d_in[25];
    const float* cnv_b = (const float*)d_in[26];
    const float* cnw_w = (const float*)d_in[27];
    const float* cnw_b = (const float*)d_in[28];

    char* w = (char*)d_ws;
    float*    S   = (float*)(w);                          // 8 MB
    float*    M   = (float*)(w + ((size_t)8  << 20));     // 8 MB
    float*    aux = (float*)(w + ((size_t)16 << 20));     // 256 KB
    ushort_t* Hhi = (ushort_t*)(w + ((size_t)17 << 20));  // 4 MB
    ushort_t* Hlo = (ushort_t*)(w + ((size_t)21 << 20));  // 4 MB
    ushort_t* Phi = (ushort_t*)(w + ((size_t)25 << 20));  // ~557 KB
    ushort_t* Plo = (ushort_t*)(w + ((size_t)26 << 20));  // ~557 KB

    float* delta_out = (float*)d_out;                      // N
    float* types_out = delta_out + N;                      // N*ALPHA
    float* cidx_out  = types_out + (size_t)N * ALPHA;      // N*(K+1)
    float* cnum_out  = cidx_out + (size_t)N * (KDEG + 1);  // N*K

    // L1: layer-0 embed + weight packing (fused, independent block ranges)
    k_embed_pack<<<3136, 256, 0, stream>>>(nt, Ws0, Wn0, b0,
                                           Ws1, Wn1, Ws2, Wn2, Wt,
                                           Hhi, Hlo, Phi, Plo);
    // L2/L3: layer 1
    k_gemm<<<512, 256, 0, stream>>>(Hhi, Hlo, Phi, Plo, Phi + 65536, Plo + 65536, S, M);
    k_combine<false><<<2048, 256, 0, stream>>>(S, M, b1, Hhi, Hlo,
                                               nullptr, nullptr, nullptr, nullptr, nullptr,
                                               nullptr, nullptr, nullptr, nullptr, nullptr,
                                               nullptr, nullptr);
    // L4/L5: layer 2 (+ scalar heads fused)
    k_gemm<<<512, 256, 0, stream>>>(Hhi, Hlo, Phi + 131072, Plo + 131072,
                                    Phi + 196608, Plo + 196608, S, M);
    k_combine<true><<<2048, 256, 0, stream>>>(S, M, b2, Hhi, Hlo,
                                              we, be, ciu_w, ciu_b, civ_w, civ_b,
                                              cnu_w, cnu_b, cnv_w, cnv_b, aux, delta_out);
    // L6: types GEMM + child heads (fused, block ranges)
    k_heads<<<128 + 2048, 256, 0, stream>>>(Hhi, Hlo, Phi + 262144, Plo + 262144, bt,
                                            aux, ciw_w, ciw_b, cnw_w, cnw_b,
                                            types_out, cidx_out, cnum_out);
}